// Round 2
// baseline (233.849 us; speedup 1.0000x reference)
//
#include <hip/hip_runtime.h>
#include <math.h>

// Problem shape (fixed by the reference): x is [B=8, S=4096, D=1024] fp32.
constexpr int B = 8;
constexpr int S = 4096;
constexpr int D = 1024;
constexpr int DQ = D / 4;            // float4 groups per row = 256
constexpr int DQ_SHIFT = 8;          // log2(DQ)
constexpr int PLANE4 = S * DQ;       // 2^20 float4 per [S,D] plane

// Native Clang vector type: __builtin_nontemporal_load/store accept this
// (HIP's float4 is a struct and is rejected).
typedef float floatx4 __attribute__((ext_vector_type(4)));

// -log2(10000) / D
#define NEG_L2_10000_OVER_D (-13.287712379549449f / 1024.0f)

// One thread per [S,D]-plane float4 position. The positional-encoding value
// depends only on (s, d), NOT on batch — so compute it once and apply to all
// 8 batch planes. PE math is expression-for-expression identical to the
// original passing kernel => bitwise-identical output (no tolerance risk).
// Per thread: 8 nontemporal 16B loads (independent, deep ILP) +
// 4 exp2 + 2 sin + 2 cos + 8 nontemporal 16B stores. Transcendental and
// index work amortized 8x vs the original kernel; nt hints because every
// byte is touched exactly once (streaming, no reuse worth caching).
__global__ __launch_bounds__(256)
void pe_add_kernel(const float* __restrict__ x, float* __restrict__ out) {
    const int t = blockIdx.x * blockDim.x + threadIdx.x;   // 0 .. PLANE4-1

    const floatx4* __restrict__ xv = (const floatx4*)x;
    floatx4*       __restrict__ ov = (floatx4*)out;

    // Issue all 8 batch loads first so their latency overlaps the PE math.
    floatx4 v[B];
#pragma unroll
    for (int b = 0; b < B; ++b)
        v[b] = __builtin_nontemporal_load(&xv[b * PLANE4 + t]);

    const int dq = t & (DQ - 1);     // float4 index within the row
    const int s  = t >> DQ_SHIFT;    // sequence position
    const int d0 = dq << 2;          // first scalar dim index of this float4

    const float fs = (float)s;
    const float a0 = fs * exp2f((float)(d0 + 0) * NEG_L2_10000_OVER_D);
    const float a1 = fs * exp2f((float)(d0 + 1) * NEG_L2_10000_OVER_D);
    const float a2 = fs * exp2f((float)(d0 + 2) * NEG_L2_10000_OVER_D);
    const float a3 = fs * exp2f((float)(d0 + 3) * NEG_L2_10000_OVER_D);

    const float p0 = __sinf(a0);     // even dim -> sin
    const float p1 = __cosf(a1);     // odd  dim -> cos
    const float p2 = __sinf(a2);
    const float p3 = __cosf(a3);

#pragma unroll
    for (int b = 0; b < B; ++b) {
        floatx4 r = v[b];
        r.x += p0;
        r.y += p1;
        r.z += p2;
        r.w += p3;
        __builtin_nontemporal_store(r, &ov[b * PLANE4 + t]);
    }
}

extern "C" void kernel_launch(void* const* d_in, const int* in_sizes, int n_in,
                              void* d_out, int out_size, void* d_ws, size_t ws_size,
                              hipStream_t stream) {
    const float* x = (const float*)d_in[0];
    float* out = (float*)d_out;

    const int threads = 256;
    const int blocks = PLANE4 / threads;   // 4096 blocks, one float4-column each
    pe_add_kernel<<<blocks, threads, 0, stream>>>(x, out);
}

// Round 3
// 227.312 us; speedup vs baseline: 1.0288x; 1.0288x over previous
//
#include <hip/hip_runtime.h>
#include <math.h>

// Problem shape (fixed by the reference): x is [B=8, S=4096, D=1024] fp32.
constexpr int B = 8;
constexpr int S = 4096;
constexpr int D = 1024;
constexpr int DQ = D / 4;            // float4 groups per row = 256
constexpr int PLANE4 = S * DQ;       // 2^20 float4 per [S,D] plane
constexpr int TOTAL4 = B * PLANE4;   // 2^23 float4 total
constexpr int CHUNK = 4;             // rows per block (256 threads = 1 row)

// -log2(10000) / D
#define NEG_L2_10000_OVER_D (-13.287712379549449f / 1024.0f)

// Each block owns a contiguous 64 KB window = 4 consecutive rows of one
// batch plane (256 float4 per row, 256 threads). A thread therefore handles
// the SAME dim-quad d0 at rows s0..s0+3:
//   - the 4 exp2f row-wave factors are computed once per thread (amortized
//     4x), sin/cos remain per element.
//   - every expression tree (fs * exp2f((d0+j)*c) -> __sinf/__cosf) is
//     token-identical to the validated Round-0 kernel => bitwise-identical
//     output, absmax unchanged.
//   - 4 burst loads, compute, 4 burst stores; all traffic inside one 64 KB
//     window per block — preserves the sequential DRAM stream locality that
//     the (regressed) 8-plane batch-reuse version destroyed.
__global__ __launch_bounds__(256)
void pe_add_kernel(const float* __restrict__ x, float* __restrict__ out) {
    const int tid  = threadIdx.x;
    const int base = blockIdx.x * (256 * CHUNK);   // float4 index of window

    const float4* __restrict__ xv = (const float4*)x;
    float4*       __restrict__ ov = (float4*)out;

    // Burst the 4 row-loads first so their latency overlaps the PE math.
    float4 v[CHUNK];
#pragma unroll
    for (int r = 0; r < CHUNK; ++r)
        v[r] = xv[base + (r << 8) + tid];

    const int d0 = tid << 2;                       // dq == tid (one row/256 thr)
    const int s0 = (base & (PLANE4 - 1)) >> 8;     // row of chunk 0

    const float w0 = exp2f((float)(d0 + 0) * NEG_L2_10000_OVER_D);
    const float w1 = exp2f((float)(d0 + 1) * NEG_L2_10000_OVER_D);
    const float w2 = exp2f((float)(d0 + 2) * NEG_L2_10000_OVER_D);
    const float w3 = exp2f((float)(d0 + 3) * NEG_L2_10000_OVER_D);

#pragma unroll
    for (int r = 0; r < CHUNK; ++r) {
        const float fs = (float)(s0 + r);
        float4 t = v[r];
        t.x += __sinf(fs * w0);   // even dim -> sin
        t.y += __cosf(fs * w1);   // odd  dim -> cos
        t.z += __sinf(fs * w2);
        t.w += __cosf(fs * w3);
        ov[base + (r << 8) + tid] = t;
    }
}

extern "C" void kernel_launch(void* const* d_in, const int* in_sizes, int n_in,
                              void* d_out, int out_size, void* d_ws, size_t ws_size,
                              hipStream_t stream) {
    const float* x = (const float*)d_in[0];
    float* out = (float*)d_out;

    const int threads = 256;
    const int blocks = TOTAL4 / (threads * CHUNK);   // 8192
    pe_add_kernel<<<blocks, threads, 0, stream>>>(x, out);
}

// Round 4
// 217.142 us; speedup vs baseline: 1.0769x; 1.0468x over previous
//
#include <hip/hip_runtime.h>
#include <math.h>

// Problem shape (fixed by the reference): x is [B=8, S=4096, D=1024] fp32.
constexpr int B = 8;
constexpr int S = 4096;
constexpr int D = 1024;
constexpr int DQ = D / 4;            // float4 groups per row = 256
constexpr int DQ_SHIFT = 8;          // log2(DQ)
constexpr int PLANE4 = S * DQ;       // 2^20 float4 per [S,D] plane
constexpr int TOTAL4 = B * PLANE4;   // 2^23 float4 total

// Native Clang vector type: __builtin_nontemporal_load/store accept this
// (HIP's float4 struct is rejected). Lowers to global_load/store_dwordx4 nt.
typedef float floatx4 __attribute__((ext_vector_type(4)));

// -log2(10000) / D
#define NEG_L2_10000_OVER_D (-13.287712379549449f / 1024.0f)

// Structure lesson from rounds 1-3: 1 float4 per thread is the FASTEST
// configuration (R1: 8/thread -> +10us, R3: 4/thread -> +8us). Multi-element
// threads push VGPR past the 64-reg occupancy boundary and halve resident
// waves; this streaming kernel lives on raw TLP (~20 VGPR here = 8 waves/SIMD,
// 2048 threads/CU). Compute is NOT the limiter (trans work ~104 issue-cy/wave
// vs ~800 cy/wave memory budget), so no amortization tricks.
//
// Single change vs the validated 219.5us baseline: nontemporal load+store.
// Zero-reuse stream -> skip L1/L2 line allocation. Same VGPRs, same
// addressing, token-identical PE math => bitwise-identical output.
__global__ __launch_bounds__(256)
void pe_add_kernel(const float* __restrict__ x, float* __restrict__ out) {
    const int idx4 = blockIdx.x * blockDim.x + threadIdx.x;  // 0 .. TOTAL4-1

    const floatx4* __restrict__ xv = (const floatx4*)x;
    floatx4*       __restrict__ ov = (floatx4*)out;

    // Issue the load first so its latency overlaps the pe computation.
    floatx4 v = __builtin_nontemporal_load(&xv[idx4]);

    const int pidx = idx4 & (PLANE4 - 1);   // position within the [S,D] plane
    const int dq   = pidx & (DQ - 1);
    const int s    = pidx >> DQ_SHIFT;
    const int d0   = dq << 2;

    const float fs = (float)s;
    const float a0 = fs * exp2f((float)(d0 + 0) * NEG_L2_10000_OVER_D);
    const float a1 = fs * exp2f((float)(d0 + 1) * NEG_L2_10000_OVER_D);
    const float a2 = fs * exp2f((float)(d0 + 2) * NEG_L2_10000_OVER_D);
    const float a3 = fs * exp2f((float)(d0 + 3) * NEG_L2_10000_OVER_D);

    v.x += __sinf(a0);   // even dim -> sin
    v.y += __cosf(a1);   // odd  dim -> cos
    v.z += __sinf(a2);
    v.w += __cosf(a3);

    __builtin_nontemporal_store(v, &ov[idx4]);
}

extern "C" void kernel_launch(void* const* d_in, const int* in_sizes, int n_in,
                              void* d_out, int out_size, void* d_ws, size_t ws_size,
                              hipStream_t stream) {
    const float* x = (const float*)d_in[0];
    float* out = (float*)d_out;

    const int threads = 256;
    const int blocks = TOTAL4 / threads;   // 32768
    pe_add_kernel<<<blocks, threads, 0, stream>>>(x, out);
}